// Round 13
// baseline (2620.865 us; speedup 1.0000x reference)
//
#include <hip/hip_runtime.h>

#define T_   256
#define HID_ 1024
#define D2   512

typedef __attribute__((ext_vector_type(8))) short  short8;
typedef __attribute__((ext_vector_type(8))) __bf16 bf16x8;
typedef __attribute__((ext_vector_type(4))) float  f32x4;

__device__ __forceinline__ float sigmoidf_(float x) {
    return __fdividef(1.0f, 1.0f + __expf(-x));
}
__device__ __forceinline__ float tanhf_(float x) {
    return 1.0f - __fdividef(2.0f, 1.0f + __expf(2.0f * x));
}
__device__ __forceinline__ unsigned short bf16hi(float x) {
    unsigned u = __float_as_uint(x);
    return (unsigned short)((u + 0x7FFFu + ((u >> 16) & 1u)) >> 16);
}
__device__ __forceinline__ float bf2f(unsigned short h) {
    return __uint_as_float((unsigned)h << 16);
}
__device__ __forceinline__ f32x4 mfma_(short8 a, short8 b, f32x4 c) {
    union { short8 s; bf16x8 b; } ua, ub;
    ua.s = a; ub.s = b;
    return __builtin_amdgcn_mfma_f32_16x16x32_bf16(ua.b, ub.b, c, 0, 0, 0);
}

// ---- raw asm memory ops (64-bit VGPR address form: works for divergent ptrs)
__device__ __forceinline__ void gl16(short8& d, const void* p) {
    asm volatile("global_load_dwordx4 %0, %1, off" : "=v"(d) : "v"(p));
}
__device__ __forceinline__ void gl16c(short8& d, const void* p) {
    asm volatile("global_load_dwordx4 %0, %1, off sc0 sc1" : "=v"(d) : "v"(p));
}
__device__ __forceinline__ void gs4c(void* p, unsigned v) {
    asm volatile("global_store_dword %0, %1, off sc0 sc1"
                 :: "v"(p), "v"(v) : "memory");
}
#define WAITV0() asm volatile("s_waitcnt vmcnt(0)" ::: "memory")
#define WAITV5() asm volatile("s_waitcnt vmcnt(5)" ::: "memory")
// ties "materialize" the A-frag regs so MFMAs can't be hoisted above the wait
#define WAITV7_T(H, L) asm volatile("s_waitcnt vmcnt(7)" : "+v"(H), "+v"(L) :: "memory")
#define WAITV2_T(H, L) asm volatile("s_waitcnt vmcnt(2)" : "+v"(H), "+v"(L) :: "memory")
#define WAITV0_T(H, L) asm volatile("s_waitcnt vmcnt(0)" : "+v"(H), "+v"(L) :: "memory")
#define ABAR() asm volatile("s_waitcnt lgkmcnt(0)\n\ts_barrier" ::: "memory")
#define PRIO1() __builtin_amdgcn_s_setprio(1)
#define PRIO0() __builtin_amdgcn_s_setprio(0)

// ---------------- prelim: W2 = fc2_w @ fc1_w, b2 = fc2_w@fc1_b + fc2_b ----
__global__ __launch_bounds__(256) void k_w2(
    const float* __restrict__ fc2_w, const float* __restrict__ fc1_w,
    const float* __restrict__ fc1_b, const float* __restrict__ fc2_b,
    float* __restrict__ W2, float* __restrict__ b2)
{
    int idx = blockIdx.x * 256 + threadIdx.x;   // 0..65535
    int r = idx >> 6, c = idx & 63;
    float acc = 0.f;
    for (int k = 0; k < D2; ++k)
        acc += fc2_w[(size_t)r * D2 + k] * fc1_w[(size_t)k * 64 + c];
    W2[idx] = acc;
    if (c == 0) {
        float a = fc2_b[r];
        for (int k = 0; k < D2; ++k)
            a += fc2_w[(size_t)r * D2 + k] * fc1_b[k];
        b2[r] = a;
    }
}

// -------- prelim: Wc = w_ih @ W2 (bf16 split planes), bc = w_ih@b2 + b_ih --
__global__ __launch_bounds__(256) void k_wc(
    const float* __restrict__ w_ih, const float* __restrict__ W2,
    const float* __restrict__ b2, const float* __restrict__ b_ih,
    unsigned short* __restrict__ wc_hi, unsigned short* __restrict__ wc_lo,
    float* __restrict__ bc)
{
    int idx = blockIdx.x * 256 + threadIdx.x;   // 0..196607
    int r = idx >> 6, c = idx & 63;
    float acc = 0.f;
    for (int k = 0; k < HID_; ++k)
        acc += w_ih[(size_t)r * HID_ + k] * W2[(size_t)k * 64 + c];
    unsigned short h = bf16hi(acc);
    wc_hi[idx] = h;
    wc_lo[idx] = bf16hi(acc - bf2f(h));
    if (c == 0) {
        float a = b_ih[r];
        for (int k = 0; k < HID_; ++k)
            a += w_ih[(size_t)r * HID_ + k] * b2[k];
        bc[r] = a;
    }
}

// ---------------- prelim: split w_hh into bf16 hi/lo planes ----------------
__global__ __launch_bounds__(256) void k_splitw(
    const float* __restrict__ w, unsigned short* __restrict__ hi,
    unsigned short* __restrict__ lo)
{
    int i4 = (blockIdx.x * 256 + threadIdx.x) * 4;
    float4 v = *(const float4*)(w + i4);
    float vv[4] = {v.x, v.y, v.z, v.w};
    unsigned short h4[4], l4[4];
    #pragma unroll
    for (int i = 0; i < 4; ++i) {
        h4[i] = bf16hi(vv[i]);
        l4[i] = bf16hi(vv[i] - bf2f(h4[i]));
    }
    *(unsigned long long*)(hi + i4) =
        (unsigned long long)h4[0] | ((unsigned long long)h4[1] << 16) |
        ((unsigned long long)h4[2] << 32) | ((unsigned long long)h4[3] << 48);
    *(unsigned long long*)(lo + i4) =
        (unsigned long long)l4[0] | ((unsigned long long)l4[1] << 16) |
        ((unsigned long long)l4[2] << 32) | ((unsigned long long)l4[3] << 48);
}

// ------- prelim: h0 -> bf16 split planes in fragment-granule layout --------
// layout: byte = (k>>5)*16384 + b*64 + ((k>>3)&3)*16 + (k&7)*2
__global__ __launch_bounds__(256) void k_split_h0(
    const float* __restrict__ hn, unsigned short* __restrict__ hi,
    unsigned short* __restrict__ lo)
{
    int gid = blockIdx.x * 256 + threadIdx.x;      // 0..32767
    int b = gid >> 7, kseg = gid & 127;
    const float* src = hn + (size_t)b * HID_ + kseg * 8;
    short8 h8, l8;
    #pragma unroll
    for (int i = 0; i < 8; ++i) {
        float v = src[i];
        unsigned short h = bf16hi(v);
        ((short*)&h8)[i] = (short)h;
        ((short*)&l8)[i] = (short)bf16hi(v - bf2f(h));
    }
    size_t off = (size_t)(kseg >> 2) * 8192 + b * 32 + (kseg & 3) * 8; // ushorts
    *(short8*)(hi + off) = h8;
    *(short8*)(lo + off) = l8;
}

// ---------------- main persistent GRU kernel (MFMA split-bf16) -------------
// R12 (on R11's 2-blocks/CU + permanent-Wc structure): T5 s_setprio around
// the MFMA clusters (gi compute + each GH_CHUNK). Per the technique catalog,
// setprio is structure-conditional: null on lockstep single-block schedules,
// positive when waves on a CU sit at DIFFERENT phases — which R10's two
// independent co-resident blocks provide (one block's MFMA burst coexists
// with the other block's staging/spin/barrier waits). setprio(1) biases the
// SIMD scheduler toward the compute wave; no memory-order, barrier, or
// numeric change -> bitwise-identical output.
__global__ __launch_bounds__(256, 2) void k_gru(
    const float* __restrict__ input,
    const float* __restrict__ hn,
    const float* __restrict__ b_hh,
    const float* __restrict__ bc,
    const unsigned short* __restrict__ whh_hi,
    const unsigned short* __restrict__ whh_lo,
    const unsigned short* __restrict__ wc_hi,
    const unsigned short* __restrict__ wc_lo,
    unsigned short* __restrict__ hxA_hi, unsigned short* __restrict__ hxA_lo,
    unsigned short* __restrict__ hxB_hi, unsigned short* __restrict__ hxB_lo,
    float* __restrict__ hn_out,
    int* __restrict__ bar)
{
    const int g = blockIdx.x, ct = g & 63, bt = g >> 6;
    const int j0 = ct << 4, b0 = bt << 5;
    const int tid = threadIdx.x, lane = tid & 63, wid = tid >> 6;
    const int mh = wid & 1, kh = wid >> 1;
    const int l15 = lane & 15, quad = lane >> 4;

    __shared__ short smB[24576];   // 3 ring bufs x 6144 + permanent Wc 6144
    float* smF = (float*)smB;      // C-dump alias (over ring bufs only)
    const int SIN_ = 2112, SHN_ = 3200, WCP = 18432;

    // ---- staging descriptors: 3 x 16B segs per thread per K64 granule ----
    // granule buf = 2 chunks x (96 rows x 32 shorts); row = pl*48 + n,
    // n = gate*16 + col16. seg = tid + i*256 in [0,768).
    const char* wB[3]; const char* cB[3]; int lo_[3];
    #pragma unroll
    for (int i = 0; i < 3; ++i) {
        int seg = tid + (i << 8);
        int cg = seg / 384, s = seg % 384;
        int row = s >> 2, ss = s & 3;
        int pln = row / 48, n = row % 48;
        int grow = (n >> 4) * HID_ + j0 + (n & 15);
        wB[i] = (const char*)(pln ? whh_lo : whh_hi)
              + (size_t)grow * 2048u + (size_t)(ss * 16 + cg * 64);
        cB[i] = (const char*)(pln ? wc_lo : wc_hi)
              + (size_t)grow * 128u + (size_t)(ss * 16 + cg * 64);
        lo_[i] = cg * 3072 + row * 32 + ((ss * 8) ^ (((row >> 1) & 3) << 3));
    }
    const int foff = l15 * 32 + ((quad * 8) ^ (((l15 >> 1) & 3) << 3));   // swz
    const size_t aoff = (size_t)((b0 + mh * 16 + l15) * 64 + quad * 16);
    const char* aAh = (const char*)hxA_hi + aoff;
    const char* aAl = (const char*)hxA_lo + aoff;
    const char* aBh = (const char*)hxB_hi + aoff;
    const char* aBl = (const char*)hxB_lo + aoff;
    const float* xrow = input + (size_t)(b0 + mh * 16 + l15) * (T_ * 64)
                              + kh * 32 + quad * 8;

    // ---- gate-phase statics: thread owns (b = b0+gb, j = j0+gj2, +1) -----
    const int gb = tid >> 3, gj2 = (tid & 7) << 1;
    float hreg[2], br[2], bz[2], bni[2], bnh[2];
    #pragma unroll
    for (int i = 0; i < 2; ++i) {
        int j = j0 + gj2 + i;
        hreg[i] = hn[(size_t)(b0 + gb) * HID_ + j];
        br[i]  = bc[j] + b_hh[j];
        bz[i]  = bc[1024 + j] + b_hh[1024 + j];
        bni[i] = bc[2048 + j];
        bnh[i] = b_hh[2048 + j];
    }
    const int j2 = j0 + gj2;
    const size_t hoff = (size_t)(j2 >> 5) * 16384 + (size_t)(b0 + gb) * 64
                      + (size_t)((j2 >> 3) & 3) * 16 + (size_t)(j2 & 7) * 2;
    char* sAh = (char*)hxA_hi + hoff; char* sAl = (char*)hxA_lo + hoff;
    char* sBh = (char*)hxB_hi + hoff; char* sBl = (char*)hxB_lo + hoff;
    const int g33 = gb * 33, g17 = gb * 17;

    int* flags = bar + bt * 128;   // 64 per-producer flags, 256B (coalesced)

    short8 bp[2][3];   // weight payload for a K64 granule, set = granule&1
    short8 ab[3][2];   // A-frag banks [granule%3][hi/lo]
    f32x4 acc[3];      // r, z, n(gh)
    f32x4 acci;        // n(gi)

    // ---- one-time: stage Wc into the permanent LDS region ----
    {
        short8 cp[3];
        #pragma unroll
        for (int j = 0; j < 3; ++j)
            gl16(cp[j], cB[j]);
        WAITV0();
        #pragma unroll
        for (int j = 0; j < 3; ++j)
            *(short8*)(smB + WCP + lo_[j]) = cp[j];
        ABAR();
    }

#define ISSUE_A(BK, C)                                                       \
  { gl16c(ab[BK][0], rh + (size_t)(C) * 16384);                              \
    gl16c(ab[BK][1], rl + (size_t)(C) * 16384); }
#define GH_CHUNK(RB, AH, AL)                                                 \
  { PRIO1();                                                                 \
    _Pragma("unroll")                                                        \
    for (int nt = 0; nt < 3; ++nt) {                                         \
        short8 bh_ = *(const short8*)(smB + (RB) + nt * 512 + foff);         \
        short8 bl_ = *(const short8*)(smB + (RB) + 1536 + nt * 512 + foff);  \
        f32x4 v_ = mfma_(AH, bh_, acc[nt]);                                  \
        v_ = mfma_(AH, bl_, v_);                                             \
        v_ = mfma_(AL, bh_, v_);                                             \
        acc[nt] = v_; }                                                      \
    PRIO0(); }

    #pragma unroll 1
    for (int t = 0; t < 256; ++t) {
        const char* rh = (t & 1) ? aBh : aAh;   // read planes (h in)
        const char* rl = (t & 1) ? aBl : aAl;
        char* wh = (t & 1) ? sAh : sBh;         // write planes (h out)
        char* wl = (t & 1) ? sAl : sBl;

        // ---- x_t load + split (plain cached loads; compiler waits) ----
        float xv[8];
        *(float4*)&xv[0] = *(const float4*)(xrow + (size_t)t * 64);
        *(float4*)&xv[4] = *(const float4*)(xrow + (size_t)t * 64 + 4);
        short8 xa_hi, xa_lo;
        #pragma unroll
        for (int i = 0; i < 8; ++i) {
            unsigned short h = bf16hi(xv[i]);
            ((short*)&xa_hi)[i] = (short)h;
            ((short*)&xa_lo)[i] = (short)bf16hi(xv[i] - bf2f(h));
        }
        WAITV0();
        // issue w_hh granules 0 and 1 pre-spin (weights step-invariant)
        #pragma unroll
        for (int j = 0; j < 3; ++j)
            gl16(bp[0][j], wB[j]);
        #pragma unroll
        for (int j = 0; j < 3; ++j)
            gl16(bp[1][j], wB[j] + 128);
        // ---- gi compute from the PERMANENT Wc region (chunk = kh) ----
        {
            const int rb = WCP + kh * 3072;
            PRIO1();
            #pragma unroll
            for (int nt = 0; nt < 3; ++nt) {
                short8 bh_ = *(const short8*)(smB + rb + nt * 512 + foff);
                short8 bl_ = *(const short8*)(smB + rb + 1536 + nt * 512 + foff);
                f32x4 z = {0.f, 0.f, 0.f, 0.f};
                f32x4 v = mfma_(xa_hi, bh_, z);
                v = mfma_(xa_hi, bl_, v);
                v = mfma_(xa_lo, bh_, v);
                if (nt < 2) { acc[nt] = v; }
                else { acci = v; acc[2] = z; }
            }
            PRIO0();
        }
        // ---- wait for h(t): parallel poll of the 64 producer flags ----
        if (t > 0 && wid == 0) {
            int fl = __hip_atomic_load(flags + lane, __ATOMIC_RELAXED,
                                       __HIP_MEMORY_SCOPE_SYSTEM);
            while (__any(fl < t)) {
                __builtin_amdgcn_s_sleep(1);
                fl = __hip_atomic_load(flags + lane, __ATOMIC_RELAXED,
                                       __HIP_MEMORY_SCOPE_SYSTEM);
            }
        }
        ABAR();
        // ---- prologue: A(granule 0), write W0 -> buf0, A(granule 1) ----
        ISSUE_A(0, kh);
        WAITV5();                  // queue {W0(3),W1(3),A0(2)} -> forces W0
        #pragma unroll
        for (int j = 0; j < 3; ++j)
            *(short8*)(smB + lo_[j]) = bp[0][j];
        ISSUE_A(1, 2 + kh);
        ABAR();
        // ---- gh pipeline: 16 K64 granules, ring-3, 1 barrier each ----
        #pragma unroll
        for (int G = 0; G < 16; ++G) {
            if (G <= 13) {
                #pragma unroll
                for (int j = 0; j < 3; ++j)
                    gl16(bp[G & 1][j], wB[j] + (size_t)(G + 2) * 128);
                ISSUE_A((G + 2) % 3, 2 * (G + 2) + kh);
                WAITV7_T(ab[G % 3][0], ab[G % 3][1]);
            } else if (G == 14) {
                WAITV2_T(ab[2][0], ab[2][1]);
            } else {
                WAITV0_T(ab[0][0], ab[0][1]);
            }
            if (G <= 14) {
                #pragma unroll
                for (int j = 0; j < 3; ++j)
                    *(short8*)(smB + ((G + 1) % 3) * 6144 + lo_[j])
                        = bp[(G + 1) & 1][j];
                ABAR();
            }
            GH_CHUNK((G % 3) * 6144 + kh * 3072, ab[G % 3][0], ab[G % 3][1]);
        }
        __syncthreads();
        // ---- dump C fragments (aliased over ring bufs) ----
        {
            const int row = mh * 16 + quad * 4;
            #pragma unroll
            for (int nt = 0; nt < 2; ++nt)
                #pragma unroll
                for (int r = 0; r < 4; ++r)
                    smF[kh * 1056 + (row + r) * 33 + nt * 16 + l15] = acc[nt][r];
            #pragma unroll
            for (int r = 0; r < 4; ++r) {
                smF[SHN_ + kh * 544 + (row + r) * 17 + l15] = acc[2][r];
                smF[SIN_ + kh * 544 + (row + r) * 17 + l15] = acci[r];
            }
        }
        __syncthreads();
        // ---- gate phase: thread owns (gb, gj2, +1); hprev in registers ----
        unsigned short ph2[2], pl2[2];
        #pragma unroll
        for (int i = 0; i < 2; ++i) {
            int cl = gj2 + i;
            float rp = smF[g33 + cl] + smF[1056 + g33 + cl] + br[i];
            float zp = smF[g33 + 16 + cl] + smF[1056 + g33 + 16 + cl] + bz[i];
            float ip = smF[SIN_ + g17 + cl] + smF[SIN_ + 544 + g17 + cl] + bni[i];
            float hp = smF[SHN_ + g17 + cl] + smF[SHN_ + 544 + g17 + cl] + bnh[i];
            float rr = sigmoidf_(rp);
            float zz = sigmoidf_(zp);
            float nn = tanhf_(ip + rr * hp);
            float hv = (1.0f - zz) * nn + zz * hreg[i];
            hreg[i] = hv;
            unsigned short hh = bf16hi(hv);
            ph2[i] = hh;
            pl2[i] = bf16hi(hv - bf2f(hh));
        }
        unsigned pk_hi = (unsigned)ph2[0] | ((unsigned)ph2[1] << 16);
        unsigned pk_lo = (unsigned)pl2[0] | ((unsigned)pl2[1] << 16);
        gs4c(wh, pk_hi);
        gs4c(wl, pk_lo);
        if (t == 255) {
            #pragma unroll
            for (int i = 0; i < 2; ++i)
                hn_out[(size_t)(b0 + gb) * HID_ + j0 + gj2 + i] = hreg[i];
        }
        WAITV0();           // h-plane stores at coherence point
        __syncthreads();    // whole block done
        if (t < 255 && tid == 0)
            __hip_atomic_store(flags + ct, t + 1, __ATOMIC_RELAXED,
                               __HIP_MEMORY_SCOPE_SYSTEM);
    }
#undef GH_CHUNK
#undef ISSUE_A
}

// ---------------- fc3: out3 = relu(relu(h) @ fc3_wT + fc3_b) --------------
__global__ __launch_bounds__(256) void k_fc3(
    const float* __restrict__ h, const float* __restrict__ fc3_w,
    const float* __restrict__ fc3_b, float* __restrict__ out3)
{
    const int bt = blockIdx.x >> 3;
    const int dt = blockIdx.x & 7;
    const int b0 = bt << 6;
    const int d0 = dt << 6;
    const int tid = threadIdx.x;
    const int tx = tid & 15, ty = tid >> 4;

    __shared__ float sh_h[64][36];
    __shared__ float sh_w[64][36];

    float acc[4][4] = {};
    const int lr = tid >> 3;
    const int lc = (tid & 7) << 2;

    for (int kk = 0; kk < HID_; kk += 32) {
        #pragma unroll
        for (int p = 0; p < 2; ++p) {
            int row = lr + (p << 5);
            float4 v = *(const float4*)(h + (size_t)(b0 + row) * HID_ + kk + lc);
            v.x = fmaxf(v.x, 0.f); v.y = fmaxf(v.y, 0.f);
            v.z = fmaxf(v.z, 0.f); v.w = fmaxf(v.w, 0.f);
            *(float4*)&sh_h[row][lc] = v;
            *(float4*)&sh_w[row][lc] =
                *(const float4*)(fc3_w + (size_t)(d0 + row) * HID_ + kk + lc);
        }
        __syncthreads();
        #pragma unroll
        for (int k = 0; k < 32; ++k) {
            float hv[4], wv[4];
            #pragma unroll
            for (int i = 0; i < 4; ++i) hv[i] = sh_h[ty + (i << 4)][k];
            #pragma unroll
            for (int q = 0; q < 4; ++q) wv[q] = sh_w[tx + (q << 4)][k];
            #pragma unroll
            for (int i = 0; i < 4; ++i)
                #pragma unroll
                for (int q = 0; q < 4; ++q)
                    acc[i][q] += hv[i] * wv[q];
        }
        __syncthreads();
    }
    #pragma unroll
    for (int i = 0; i < 4; ++i) {
        int b = b0 + ty + (i << 4);
        #pragma unroll
        for (int q = 0; q < 4; ++q) {
            int d = d0 + tx + (q << 4);
            out3[(size_t)b * D2 + d] = fmaxf(acc[i][q] + fc3_b[d], 0.f);
        }
    }
}

// ---------------- heads: params[b,o] = out3[b,:]·heads_w[cid[b],o,:]+b ----
__global__ __launch_bounds__(256) void k_heads(
    const float* __restrict__ out3, const int* __restrict__ cult,
    const float* __restrict__ hw, const float* __restrict__ hb,
    float* __restrict__ params)
{
    int b = blockIdx.x;
    int o = threadIdx.x >> 4;
    int l = threadIdx.x & 15;
    int cid = cult[b];
    const float* w = hw + ((size_t)cid * 16 + o) * D2;
    const float* x = out3 + (size_t)b * D2;
    float acc = 0.f;
    #pragma unroll
    for (int m = 0; m < 8; ++m) {
        int d4 = (l + (m << 4)) << 2;
        float4 xv = *(const float4*)(x + d4);
        float4 wv = *(const float4*)(w + d4);
        acc += xv.x * wv.x + xv.y * wv.y + xv.z * wv.z + xv.w * wv.w;
    }
    #pragma unroll
    for (int s = 1; s < 16; s <<= 1)
        acc += __shfl_xor(acc, s, 16);
    if (l == 0)
        params[(size_t)b * 16 + o] = acc + hb[(size_t)cid * 16 + o];
}

extern "C" void kernel_launch(void* const* d_in, const int* in_sizes, int n_in,
                              void* d_out, int out_size, void* d_ws, size_t ws_size,
                              hipStream_t stream)
{
    const float* input = (const float*)d_in[0];
    const float* hn    = (const float*)d_in[1];
    const int*   cult  = (const int*)d_in[2];
    const float* fc1_w = (const float*)d_in[3];
    const float* fc1_b = (const float*)d_in[4];
    const float* fc2_w = (const float*)d_in[5];
    const float* fc2_b = (const float*)d_in[6];
    const float* w_ih  = (const float*)d_in[7];
    const float* w_hh  = (const float*)d_in[8];
    const float* b_ih  = (const float*)d_in[9];
    const float* b_hh  = (const float*)d_in[10];
    const float* fc3_w = (const float*)d_in[11];
    const float* fc3_b = (const float*)d_in[12];
    const float* hw    = (const float*)d_in[13];
    const float* hb    = (const float*)d_in[14];
    float* out = (float*)d_out;
    float* hn_out = out + 4096;          // params 256*16, then hn 256*1024

    char* ws = (char*)d_ws;
    int*   bar    = (int*)ws;                                   // 4 KB
    float* W2     = (float*)(ws + 4096);                        // 256 KB
    float* b2     = (float*)(ws + 266240);
    float* bc     = (float*)(ws + 270336);
    unsigned short* whh_hi = (unsigned short*)(ws + 282624);    // 6 MB
    unsigned short* whh_lo = (unsigned short*)(ws + 282624 + 6291456);
    unsigned short* wc_hi  = (unsigned short*)(ws + 12865536);
    unsigned short* wc_lo  = (unsigned short*)(ws + 13258752);
    unsigned short* hxA_hi = (unsigned short*)(ws + 13651968);
    unsigned short* hxA_lo = (unsigned short*)(ws + 14176256);
    unsigned short* hxB_hi = (unsigned short*)(ws + 14700544);
    unsigned short* hxB_lo = (unsigned short*)(ws + 15224832);
    float* out3   = (float*)(ws + 15749120);                    // 512 KB

    hipMemsetAsync(bar, 0, 4096, stream);
    k_w2<<<256, 256, 0, stream>>>(fc2_w, fc1_w, fc1_b, fc2_b, W2, b2);
    k_wc<<<768, 256, 0, stream>>>(w_ih, W2, b2, b_ih, wc_hi, wc_lo, bc);
    k_splitw<<<3072, 256, 0, stream>>>(w_hh, whh_hi, whh_lo);
    k_split_h0<<<128, 256, 0, stream>>>(hn, hxA_hi, hxA_lo);
    k_gru<<<512, 256, 0, stream>>>(input, hn, b_hh, bc,
                                   whh_hi, whh_lo, wc_hi, wc_lo,
                                   hxA_hi, hxA_lo, hxB_hi, hxB_lo,
                                   hn_out, bar);
    k_fc3<<<32, 256, 0, stream>>>(hn_out, fc3_w, fc3_b, out3);
    k_heads<<<256, 256, 0, stream>>>(out3, cult, hw, hb, out);
}

// Round 14
// 2569.268 us; speedup vs baseline: 1.0201x; 1.0201x over previous
//
#include <hip/hip_runtime.h>

#define T_   256
#define HID_ 1024
#define D2   512

typedef __attribute__((ext_vector_type(8))) short  short8;
typedef __attribute__((ext_vector_type(8))) __bf16 bf16x8;
typedef __attribute__((ext_vector_type(4))) float  f32x4;

__device__ __forceinline__ float sigmoidf_(float x) {
    return __fdividef(1.0f, 1.0f + __expf(-x));
}
__device__ __forceinline__ float tanhf_(float x) {
    return 1.0f - __fdividef(2.0f, 1.0f + __expf(2.0f * x));
}
__device__ __forceinline__ unsigned short bf16hi(float x) {
    unsigned u = __float_as_uint(x);
    return (unsigned short)((u + 0x7FFFu + ((u >> 16) & 1u)) >> 16);
}
__device__ __forceinline__ float bf2f(unsigned short h) {
    return __uint_as_float((unsigned)h << 16);
}
__device__ __forceinline__ f32x4 mfma_(short8 a, short8 b, f32x4 c) {
    union { short8 s; bf16x8 b; } ua, ub;
    ua.s = a; ub.s = b;
    return __builtin_amdgcn_mfma_f32_16x16x32_bf16(ua.b, ub.b, c, 0, 0, 0);
}

// ---- raw asm memory ops (64-bit VGPR address form: works for divergent ptrs)
__device__ __forceinline__ void gl16(short8& d, const void* p) {
    asm volatile("global_load_dwordx4 %0, %1, off" : "=v"(d) : "v"(p));
}
__device__ __forceinline__ void gl16c(short8& d, const void* p) {
    asm volatile("global_load_dwordx4 %0, %1, off sc0 sc1" : "=v"(d) : "v"(p));
}
__device__ __forceinline__ void gs4c(void* p, unsigned v) {
    asm volatile("global_store_dword %0, %1, off sc0 sc1"
                 :: "v"(p), "v"(v) : "memory");
}
#define WAITV0() asm volatile("s_waitcnt vmcnt(0)" ::: "memory")
#define WAITV5() asm volatile("s_waitcnt vmcnt(5)" ::: "memory")
// ties "materialize" the A-frag regs so MFMAs can't be hoisted above the wait
#define WAITV7_T(H, L) asm volatile("s_waitcnt vmcnt(7)" : "+v"(H), "+v"(L) :: "memory")
#define WAITV2_T(H, L) asm volatile("s_waitcnt vmcnt(2)" : "+v"(H), "+v"(L) :: "memory")
#define WAITV0_T(H, L) asm volatile("s_waitcnt vmcnt(0)" : "+v"(H), "+v"(L) :: "memory")
#define ABAR() asm volatile("s_waitcnt lgkmcnt(0)\n\ts_barrier" ::: "memory")

// ---------------- prelim: W2 = fc2_w @ fc1_w, b2 = fc2_w@fc1_b + fc2_b ----
__global__ __launch_bounds__(256) void k_w2(
    const float* __restrict__ fc2_w, const float* __restrict__ fc1_w,
    const float* __restrict__ fc1_b, const float* __restrict__ fc2_b,
    float* __restrict__ W2, float* __restrict__ b2)
{
    int idx = blockIdx.x * 256 + threadIdx.x;   // 0..65535
    int r = idx >> 6, c = idx & 63;
    float acc = 0.f;
    for (int k = 0; k < D2; ++k)
        acc += fc2_w[(size_t)r * D2 + k] * fc1_w[(size_t)k * 64 + c];
    W2[idx] = acc;
    if (c == 0) {
        float a = fc2_b[r];
        for (int k = 0; k < D2; ++k)
            a += fc2_w[(size_t)r * D2 + k] * fc1_b[k];
        b2[r] = a;
    }
}

// -------- prelim: Wc = w_ih @ W2 (bf16 split planes), bc = w_ih@b2 + b_ih --
__global__ __launch_bounds__(256) void k_wc(
    const float* __restrict__ w_ih, const float* __restrict__ W2,
    const float* __restrict__ b2, const float* __restrict__ b_ih,
    unsigned short* __restrict__ wc_hi, unsigned short* __restrict__ wc_lo,
    float* __restrict__ bc)
{
    int idx = blockIdx.x * 256 + threadIdx.x;   // 0..196607
    int r = idx >> 6, c = idx & 63;
    float acc = 0.f;
    for (int k = 0; k < HID_; ++k)
        acc += w_ih[(size_t)r * HID_ + k] * W2[(size_t)k * 64 + c];
    unsigned short h = bf16hi(acc);
    wc_hi[idx] = h;
    wc_lo[idx] = bf16hi(acc - bf2f(h));
    if (c == 0) {
        float a = b_ih[r];
        for (int k = 0; k < HID_; ++k)
            a += w_ih[(size_t)r * HID_ + k] * b2[k];
        bc[r] = a;
    }
}

// ---------------- prelim: split w_hh into bf16 hi/lo planes ----------------
__global__ __launch_bounds__(256) void k_splitw(
    const float* __restrict__ w, unsigned short* __restrict__ hi,
    unsigned short* __restrict__ lo)
{
    int i4 = (blockIdx.x * 256 + threadIdx.x) * 4;
    float4 v = *(const float4*)(w + i4);
    float vv[4] = {v.x, v.y, v.z, v.w};
    unsigned short h4[4], l4[4];
    #pragma unroll
    for (int i = 0; i < 4; ++i) {
        h4[i] = bf16hi(vv[i]);
        l4[i] = bf16hi(vv[i] - bf2f(h4[i]));
    }
    *(unsigned long long*)(hi + i4) =
        (unsigned long long)h4[0] | ((unsigned long long)h4[1] << 16) |
        ((unsigned long long)h4[2] << 32) | ((unsigned long long)h4[3] << 48);
    *(unsigned long long*)(lo + i4) =
        (unsigned long long)l4[0] | ((unsigned long long)l4[1] << 16) |
        ((unsigned long long)l4[2] << 32) | ((unsigned long long)l4[3] << 48);
}

// ------- prelim: h0 -> bf16 split planes in fragment-granule layout --------
// layout: byte = (k>>5)*16384 + b*64 + ((k>>3)&3)*16 + (k&7)*2
__global__ __launch_bounds__(256) void k_split_h0(
    const float* __restrict__ hn, unsigned short* __restrict__ hi,
    unsigned short* __restrict__ lo)
{
    int gid = blockIdx.x * 256 + threadIdx.x;      // 0..32767
    int b = gid >> 7, kseg = gid & 127;
    const float* src = hn + (size_t)b * HID_ + kseg * 8;
    short8 h8, l8;
    #pragma unroll
    for (int i = 0; i < 8; ++i) {
        float v = src[i];
        unsigned short h = bf16hi(v);
        ((short*)&h8)[i] = (short)h;
        ((short*)&l8)[i] = (short)bf16hi(v - bf2f(h));
    }
    size_t off = (size_t)(kseg >> 2) * 8192 + b * 32 + (kseg & 3) * 8; // ushorts
    *(short8*)(hi + off) = h8;
    *(short8*)(lo + off) = l8;
}

// ---------------- main persistent GRU kernel (MFMA split-bf16) -------------
// R13 = exact revert to R11 (measured best: 2579 us; R12's setprio was
// neutral-to-negative and is removed). Structure: 512 blocks (ct 0..63 x
// bt 0..7, 16 h-cols each), 2 blocks/CU, permanent Wc in LDS, ring-3 K64
// granules with counted vmcnt, flag-based cross-XCD handshake.
// Structural floor (measured over R4-R12): serial T=256 recurrence; per
// step = skinny GEMM (1.6 GFLOP) + cross-XCD h-broadcast + 15 barrier
// intervals; no pipe >23% — the dependency chain, not a pipe, is binding.
__global__ __launch_bounds__(256, 2) void k_gru(
    const float* __restrict__ input,
    const float* __restrict__ hn,
    const float* __restrict__ b_hh,
    const float* __restrict__ bc,
    const unsigned short* __restrict__ whh_hi,
    const unsigned short* __restrict__ whh_lo,
    const unsigned short* __restrict__ wc_hi,
    const unsigned short* __restrict__ wc_lo,
    unsigned short* __restrict__ hxA_hi, unsigned short* __restrict__ hxA_lo,
    unsigned short* __restrict__ hxB_hi, unsigned short* __restrict__ hxB_lo,
    float* __restrict__ hn_out,
    int* __restrict__ bar)
{
    const int g = blockIdx.x, ct = g & 63, bt = g >> 6;
    const int j0 = ct << 4, b0 = bt << 5;
    const int tid = threadIdx.x, lane = tid & 63, wid = tid >> 6;
    const int mh = wid & 1, kh = wid >> 1;
    const int l15 = lane & 15, quad = lane >> 4;

    __shared__ short smB[24576];   // 3 ring bufs x 6144 + permanent Wc 6144
    float* smF = (float*)smB;      // C-dump alias (over ring bufs only)
    const int SIN_ = 2112, SHN_ = 3200, WCP = 18432;

    // ---- staging descriptors: 3 x 16B segs per thread per K64 granule ----
    // granule buf = 2 chunks x (96 rows x 32 shorts); row = pl*48 + n,
    // n = gate*16 + col16. seg = tid + i*256 in [0,768).
    const char* wB[3]; const char* cB[3]; int lo_[3];
    #pragma unroll
    for (int i = 0; i < 3; ++i) {
        int seg = tid + (i << 8);
        int cg = seg / 384, s = seg % 384;
        int row = s >> 2, ss = s & 3;
        int pln = row / 48, n = row % 48;
        int grow = (n >> 4) * HID_ + j0 + (n & 15);
        wB[i] = (const char*)(pln ? whh_lo : whh_hi)
              + (size_t)grow * 2048u + (size_t)(ss * 16 + cg * 64);
        cB[i] = (const char*)(pln ? wc_lo : wc_hi)
              + (size_t)grow * 128u + (size_t)(ss * 16 + cg * 64);
        lo_[i] = cg * 3072 + row * 32 + ((ss * 8) ^ (((row >> 1) & 3) << 3));
    }
    const int foff = l15 * 32 + ((quad * 8) ^ (((l15 >> 1) & 3) << 3));   // swz
    const size_t aoff = (size_t)((b0 + mh * 16 + l15) * 64 + quad * 16);
    const char* aAh = (const char*)hxA_hi + aoff;
    const char* aAl = (const char*)hxA_lo + aoff;
    const char* aBh = (const char*)hxB_hi + aoff;
    const char* aBl = (const char*)hxB_lo + aoff;
    const float* xrow = input + (size_t)(b0 + mh * 16 + l15) * (T_ * 64)
                              + kh * 32 + quad * 8;

    // ---- gate-phase statics: thread owns (b = b0+gb, j = j0+gj2, +1) -----
    const int gb = tid >> 3, gj2 = (tid & 7) << 1;
    float hreg[2], br[2], bz[2], bni[2], bnh[2];
    #pragma unroll
    for (int i = 0; i < 2; ++i) {
        int j = j0 + gj2 + i;
        hreg[i] = hn[(size_t)(b0 + gb) * HID_ + j];
        br[i]  = bc[j] + b_hh[j];
        bz[i]  = bc[1024 + j] + b_hh[1024 + j];
        bni[i] = bc[2048 + j];
        bnh[i] = b_hh[2048 + j];
    }
    const int j2 = j0 + gj2;
    const size_t hoff = (size_t)(j2 >> 5) * 16384 + (size_t)(b0 + gb) * 64
                      + (size_t)((j2 >> 3) & 3) * 16 + (size_t)(j2 & 7) * 2;
    char* sAh = (char*)hxA_hi + hoff; char* sAl = (char*)hxA_lo + hoff;
    char* sBh = (char*)hxB_hi + hoff; char* sBl = (char*)hxB_lo + hoff;
    const int g33 = gb * 33, g17 = gb * 17;

    int* flags = bar + bt * 128;   // 64 per-producer flags, 256B (coalesced)

    short8 bp[2][3];   // weight payload for a K64 granule, set = granule&1
    short8 ab[3][2];   // A-frag banks [granule%3][hi/lo]
    f32x4 acc[3];      // r, z, n(gh)
    f32x4 acci;        // n(gi)

    // ---- one-time: stage Wc into the permanent LDS region ----
    {
        short8 cp[3];
        #pragma unroll
        for (int j = 0; j < 3; ++j)
            gl16(cp[j], cB[j]);
        WAITV0();
        #pragma unroll
        for (int j = 0; j < 3; ++j)
            *(short8*)(smB + WCP + lo_[j]) = cp[j];
        ABAR();
    }

#define ISSUE_A(BK, C)                                                       \
  { gl16c(ab[BK][0], rh + (size_t)(C) * 16384);                              \
    gl16c(ab[BK][1], rl + (size_t)(C) * 16384); }
#define GH_CHUNK(RB, AH, AL)                                                 \
  { _Pragma("unroll")                                                        \
    for (int nt = 0; nt < 3; ++nt) {                                         \
        short8 bh_ = *(const short8*)(smB + (RB) + nt * 512 + foff);         \
        short8 bl_ = *(const short8*)(smB + (RB) + 1536 + nt * 512 + foff);  \
        f32x4 v_ = mfma_(AH, bh_, acc[nt]);                                  \
        v_ = mfma_(AH, bl_, v_);                                             \
        v_ = mfma_(AL, bh_, v_);                                             \
        acc[nt] = v_; } }

    #pragma unroll 1
    for (int t = 0; t < 256; ++t) {
        const char* rh = (t & 1) ? aBh : aAh;   // read planes (h in)
        const char* rl = (t & 1) ? aBl : aAl;
        char* wh = (t & 1) ? sAh : sBh;         // write planes (h out)
        char* wl = (t & 1) ? sAl : sBl;

        // ---- x_t load + split (plain cached loads; compiler waits) ----
        float xv[8];
        *(float4*)&xv[0] = *(const float4*)(xrow + (size_t)t * 64);
        *(float4*)&xv[4] = *(const float4*)(xrow + (size_t)t * 64 + 4);
        short8 xa_hi, xa_lo;
        #pragma unroll
        for (int i = 0; i < 8; ++i) {
            unsigned short h = bf16hi(xv[i]);
            ((short*)&xa_hi)[i] = (short)h;
            ((short*)&xa_lo)[i] = (short)bf16hi(xv[i] - bf2f(h));
        }
        WAITV0();
        // issue w_hh granules 0 and 1 pre-spin (weights step-invariant)
        #pragma unroll
        for (int j = 0; j < 3; ++j)
            gl16(bp[0][j], wB[j]);
        #pragma unroll
        for (int j = 0; j < 3; ++j)
            gl16(bp[1][j], wB[j] + 128);
        // ---- gi compute from the PERMANENT Wc region (chunk = kh) ----
        {
            const int rb = WCP + kh * 3072;
            #pragma unroll
            for (int nt = 0; nt < 3; ++nt) {
                short8 bh_ = *(const short8*)(smB + rb + nt * 512 + foff);
                short8 bl_ = *(const short8*)(smB + rb + 1536 + nt * 512 + foff);
                f32x4 z = {0.f, 0.f, 0.f, 0.f};
                f32x4 v = mfma_(xa_hi, bh_, z);
                v = mfma_(xa_hi, bl_, v);
                v = mfma_(xa_lo, bh_, v);
                if (nt < 2) { acc[nt] = v; }
                else { acci = v; acc[2] = z; }
            }
        }
        // ---- wait for h(t): parallel poll of the 64 producer flags ----
        if (t > 0 && wid == 0) {
            int fl = __hip_atomic_load(flags + lane, __ATOMIC_RELAXED,
                                       __HIP_MEMORY_SCOPE_SYSTEM);
            while (__any(fl < t)) {
                __builtin_amdgcn_s_sleep(1);
                fl = __hip_atomic_load(flags + lane, __ATOMIC_RELAXED,
                                       __HIP_MEMORY_SCOPE_SYSTEM);
            }
        }
        ABAR();
        // ---- prologue: A(granule 0), write W0 -> buf0, A(granule 1) ----
        ISSUE_A(0, kh);
        WAITV5();                  // queue {W0(3),W1(3),A0(2)} -> forces W0
        #pragma unroll
        for (int j = 0; j < 3; ++j)
            *(short8*)(smB + lo_[j]) = bp[0][j];
        ISSUE_A(1, 2 + kh);
        ABAR();
        // ---- gh pipeline: 16 K64 granules, ring-3, 1 barrier each ----
        #pragma unroll
        for (int G = 0; G < 16; ++G) {
            if (G <= 13) {
                #pragma unroll
                for (int j = 0; j < 3; ++j)
                    gl16(bp[G & 1][j], wB[j] + (size_t)(G + 2) * 128);
                ISSUE_A((G + 2) % 3, 2 * (G + 2) + kh);
                WAITV7_T(ab[G % 3][0], ab[G % 3][1]);
            } else if (G == 14) {
                WAITV2_T(ab[2][0], ab[2][1]);
            } else {
                WAITV0_T(ab[0][0], ab[0][1]);
            }
            if (G <= 14) {
                #pragma unroll
                for (int j = 0; j < 3; ++j)
                    *(short8*)(smB + ((G + 1) % 3) * 6144 + lo_[j])
                        = bp[(G + 1) & 1][j];
                ABAR();
            }
            GH_CHUNK((G % 3) * 6144 + kh * 3072, ab[G % 3][0], ab[G % 3][1]);
        }
        __syncthreads();
        // ---- dump C fragments (aliased over ring bufs) ----
        {
            const int row = mh * 16 + quad * 4;
            #pragma unroll
            for (int nt = 0; nt < 2; ++nt)
                #pragma unroll
                for (int r = 0; r < 4; ++r)
                    smF[kh * 1056 + (row + r) * 33 + nt * 16 + l15] = acc[nt][r];
            #pragma unroll
            for (int r = 0; r < 4; ++r) {
                smF[SHN_ + kh * 544 + (row + r) * 17 + l15] = acc[2][r];
                smF[SIN_ + kh * 544 + (row + r) * 17 + l15] = acci[r];
            }
        }
        __syncthreads();
        // ---- gate phase: thread owns (gb, gj2, +1); hprev in registers ----
        unsigned short ph2[2], pl2[2];
        #pragma unroll
        for (int i = 0; i < 2; ++i) {
            int cl = gj2 + i;
            float rp = smF[g33 + cl] + smF[1056 + g33 + cl] + br[i];
            float zp = smF[g33 + 16 + cl] + smF[1056 + g33 + 16 + cl] + bz[i];
            float ip = smF[SIN_ + g17 + cl] + smF[SIN_ + 544 + g17 + cl] + bni[i];
            float hp = smF[SHN_ + g17 + cl] + smF[SHN_ + 544 + g17 + cl] + bnh[i];
            float rr = sigmoidf_(rp);
            float zz = sigmoidf_(zp);
            float nn = tanhf_(ip + rr * hp);
            float hv = (1.0f - zz) * nn + zz * hreg[i];
            hreg[i] = hv;
            unsigned short hh = bf16hi(hv);
            ph2[i] = hh;
            pl2[i] = bf16hi(hv - bf2f(hh));
        }
        unsigned pk_hi = (unsigned)ph2[0] | ((unsigned)ph2[1] << 16);
        unsigned pk_lo = (unsigned)pl2[0] | ((unsigned)pl2[1] << 16);
        gs4c(wh, pk_hi);
        gs4c(wl, pk_lo);
        if (t == 255) {
            #pragma unroll
            for (int i = 0; i < 2; ++i)
                hn_out[(size_t)(b0 + gb) * HID_ + j0 + gj2 + i] = hreg[i];
        }
        WAITV0();           // h-plane stores at coherence point
        __syncthreads();    // whole block done
        if (t < 255 && tid == 0)
            __hip_atomic_store(flags + ct, t + 1, __ATOMIC_RELAXED,
                               __HIP_MEMORY_SCOPE_SYSTEM);
    }
#undef GH_CHUNK
#undef ISSUE_A
}

// ---------------- fc3: out3 = relu(relu(h) @ fc3_wT + fc3_b) --------------
__global__ __launch_bounds__(256) void k_fc3(
    const float* __restrict__ h, const float* __restrict__ fc3_w,
    const float* __restrict__ fc3_b, float* __restrict__ out3)
{
    const int bt = blockIdx.x >> 3;
    const int dt = blockIdx.x & 7;
    const int b0 = bt << 6;
    const int d0 = dt << 6;
    const int tid = threadIdx.x;
    const int tx = tid & 15, ty = tid >> 4;

    __shared__ float sh_h[64][36];
    __shared__ float sh_w[64][36];

    float acc[4][4] = {};
    const int lr = tid >> 3;
    const int lc = (tid & 7) << 2;

    for (int kk = 0; kk < HID_; kk += 32) {
        #pragma unroll
        for (int p = 0; p < 2; ++p) {
            int row = lr + (p << 5);
            float4 v = *(const float4*)(h + (size_t)(b0 + row) * HID_ + kk + lc);
            v.x = fmaxf(v.x, 0.f); v.y = fmaxf(v.y, 0.f);
            v.z = fmaxf(v.z, 0.f); v.w = fmaxf(v.w, 0.f);
            *(float4*)&sh_h[row][lc] = v;
            *(float4*)&sh_w[row][lc] =
                *(const float4*)(fc3_w + (size_t)(d0 + row) * HID_ + kk + lc);
        }
        __syncthreads();
        #pragma unroll
        for (int k = 0; k < 32; ++k) {
            float hv[4], wv[4];
            #pragma unroll
            for (int i = 0; i < 4; ++i) hv[i] = sh_h[ty + (i << 4)][k];
            #pragma unroll
            for (int q = 0; q < 4; ++q) wv[q] = sh_w[tx + (q << 4)][k];
            #pragma unroll
            for (int i = 0; i < 4; ++i)
                #pragma unroll
                for (int q = 0; q < 4; ++q)
                    acc[i][q] += hv[i] * wv[q];
        }
        __syncthreads();
    }
    #pragma unroll
    for (int i = 0; i < 4; ++i) {
        int b = b0 + ty + (i << 4);
        #pragma unroll
        for (int q = 0; q < 4; ++q) {
            int d = d0 + tx + (q << 4);
            out3[(size_t)b * D2 + d] = fmaxf(acc[i][q] + fc3_b[d], 0.f);
        }
    }
}

// ---------------- heads: params[b,o] = out3[b,:]·heads_w[cid[b],o,:]+b ----
__global__ __launch_bounds__(256) void k_heads(
    const float* __restrict__ out3, const int* __restrict__ cult,
    const float* __restrict__ hw, const float* __restrict__ hb,
    float* __restrict__ params)
{
    int b = blockIdx.x;
    int o = threadIdx.x >> 4;
    int l = threadIdx.x & 15;
    int cid = cult[b];
    const float* w = hw + ((size_t)cid * 16 + o) * D2;
    const float* x = out3 + (size_t)b * D2;
    float acc = 0.f;
    #pragma unroll
    for (int m = 0; m < 8; ++m) {
        int d4 = (l + (m << 4)) << 2;
        float4 xv = *(const float4*)(x + d4);
        float4 wv = *(const float4*)(w + d4);
        acc += xv.x * wv.x + xv.y * wv.y + xv.z * wv.z + xv.w * wv.w;
    }
    #pragma unroll
    for (int s = 1; s < 16; s <<= 1)
        acc += __shfl_xor(acc, s, 16);
    if (l == 0)
        params[(size_t)b * 16 + o] = acc + hb[(size_t)cid * 16 + o];
}

extern "C" void kernel_launch(void* const* d_in, const int* in_sizes, int n_in,
                              void* d_out, int out_size, void* d_ws, size_t ws_size,
                              hipStream_t stream)
{
    const float* input = (const float*)d_in[0];
    const float* hn    = (const float*)d_in[1];
    const int*   cult  = (const int*)d_in[2];
    const float* fc1_w = (const float*)d_in[3];
    const float* fc1_b = (const float*)d_in[4];
    const float* fc2_w = (const float*)d_in[5];
    const float* fc2_b = (const float*)d_in[6];
    const float* w_ih  = (const float*)d_in[7];
    const float* w_hh  = (const float*)d_in[8];
    const float* b_ih  = (const float*)d_in[9];
    const float* b_hh  = (const float*)d_in[10];
    const float* fc3_w = (const float*)d_in[11];
    const float* fc3_b = (const float*)d_in[12];
    const float* hw    = (const float*)d_in[13];
    const float* hb    = (const float*)d_in[14];
    float* out = (float*)d_out;
    float* hn_out = out + 4096;          // params 256*16, then hn 256*1024

    char* ws = (char*)d_ws;
    int*   bar    = (int*)ws;                                   // 4 KB
    float* W2     = (float*)(ws + 4096);                        // 256 KB
    float* b2     = (float*)(ws + 266240);
    float* bc     = (float*)(ws + 270336);
    unsigned short* whh_hi = (unsigned short*)(ws + 282624);    // 6 MB
    unsigned short* whh_lo = (unsigned short*)(ws + 282624 + 6291456);
    unsigned short* wc_hi  = (unsigned short*)(ws + 12865536);
    unsigned short* wc_lo  = (unsigned short*)(ws + 13258752);
    unsigned short* hxA_hi = (unsigned short*)(ws + 13651968);
    unsigned short* hxA_lo = (unsigned short*)(ws + 14176256);
    unsigned short* hxB_hi = (unsigned short*)(ws + 14700544);
    unsigned short* hxB_lo = (unsigned short*)(ws + 15224832);
    float* out3   = (float*)(ws + 15749120);                    // 512 KB

    hipMemsetAsync(bar, 0, 4096, stream);
    k_w2<<<256, 256, 0, stream>>>(fc2_w, fc1_w, fc1_b, fc2_b, W2, b2);
    k_wc<<<768, 256, 0, stream>>>(w_ih, W2, b2, b_ih, wc_hi, wc_lo, bc);
    k_splitw<<<3072, 256, 0, stream>>>(w_hh, whh_hi, whh_lo);
    k_split_h0<<<128, 256, 0, stream>>>(hn, hxA_hi, hxA_lo);
    k_gru<<<512, 256, 0, stream>>>(input, hn, b_hh, bc,
                                   whh_hi, whh_lo, wc_hi, wc_lo,
                                   hxA_hi, hxA_lo, hxB_hi, hxB_lo,
                                   hn_out, bar);
    k_fc3<<<32, 256, 0, stream>>>(hn_out, fc3_w, fc3_b, out3);
    k_heads<<<256, 256, 0, stream>>>(out3, cult, hw, hb, out);
}